// Round 14
// baseline (133.088 us; speedup 1.0000x reference)
//
#include <hip/hip_runtime.h>

#define BK 32          // fp32 k-elements per pipeline stage (128 B per row-visit)
#define NCHUNK 256     // grid = K-chunks; KC = D/NCHUNK = 1024
#define THREADS 1024

typedef float f32x4 __attribute__((ext_vector_type(4)));
typedef short s16x8 __attribute__((ext_vector_type(8)));

// HW packed fp32->bf16 RTNE (2 elems/instr); validated R11/R13 (absmax 0.0).
__device__ __forceinline__ unsigned cvtpk(float lo, float hi) {
  unsigned r;
  asm("v_cvt_pk_bf16_f32 %0, %1, %2" : "=v"(r) : "v"(lo), "v"(hi));
  return r;
}

__device__ __forceinline__ s16x8 cvt8(f32x4 a, f32x4 b) {
  union { unsigned u[4]; s16x8 v; } r;
  r.u[0] = cvtpk(a[0], a[1]);
  r.u[1] = cvtpk(a[2], a[3]);
  r.u[2] = cvtpk(b[0], b[1]);
  r.u[3] = cvtpk(b[2], b[3]);
  return r.v;
}

__global__ void __launch_bounds__(64) zero_kernel(float* out) {
  if (threadIdx.x == 0) out[0] = 0.f;
}

// R14 = R13 (132.9 us) + split-phase DMA issue (B-loader waves re-issue
// right after the B-read barrier -> next-next-stage loads get a ~2-3k cycle
// head start over R13's end-of-stage issue; in-flight depth during the
// A/MFMA phase rises 4->6-8 loads/wave, zero extra registers).
// GEMM core unchanged: split-K, block b owns chunk [b*KC,(b+1)*KC), full
// 256x256 fp16 partial; fp32 LDS ring-2 (128 KiB), global_load_lds DMA,
// counted vmcnt(4), per-block k-phase rotation, cvtpk conversion.
__global__ void __launch_bounds__(THREADS, 4)
gemm_kernel(const float* __restrict__ V1, const float* __restrict__ V2,
            _Float16* __restrict__ ws, int D, int KC) {
  __shared__ __align__(16) float lds[2 * 2 * 256 * BK];  // 128 KiB

  const int tid  = threadIdx.x;
  const int lane = tid & 63;
  const int wid  = tid >> 6;    // 0..15
  const int wm   = wid >> 2;    // 0..3 (M)
  const int wn   = wid & 3;     // 0..3 (N)
  const int lr   = lane & 15;
  const int lg   = lane >> 4;
  const int ns   = KC / BK;     // 32 (power of 2)
  const int nsm  = ns - 1;
  const int s0   = blockIdx.x & nsm;   // per-block k-phase rotation (R12: +4%)

  // loader role: wave covers a 32-row panel of ONE matrix (waves 0-7: V1/A,
  // waves 8-15: V2/B); 4 DMA instrs x 8 rows each.
  const int mat   = wid >> 3;         // 0: A-loader, 1: B-loader
  const int panel = (wid & 7) * 32;
  const int lrow8 = lane >> 3;        // row within an 8-row group
  const int lseg  = lane & 7;         // 16B segment
  const int swz   = (lseg * 4) ^ (lrow8 << 2);   // pre-swizzled source offset

  const float* srcM = mat ? V2 : V1;
  const size_t chunk = (size_t)blockIdx.x * (size_t)KC;
  const float* gsrc[4];
#pragma unroll
  for (int i = 0; i < 4; ++i)
    gsrc[i] = srcM + (size_t)(panel + i * 8 + lrow8) * (size_t)D + chunk + swz;

  auto issue = [&](int t, int s) {
    const int tr = (t + s0) & nsm;     // rotated k-window
#pragma unroll
    for (int i = 0; i < 4; ++i) {
      const float* g = gsrc[i] + (size_t)tr * BK;
      float* l = &lds[(((s * 2 + mat) * 256) + panel + i * 8) * BK];  // wave-uniform
      __builtin_amdgcn_global_load_lds(
          (const __attribute__((address_space(1))) void*)g,
          (__attribute__((address_space(3))) void*)l, 16, 0, 0);
    }
  };

  f32x4 acc[4][4];
#pragma unroll
  for (int a = 0; a < 4; ++a)
#pragma unroll
    for (int b = 0; b < 4; ++b) acc[a][b] = f32x4{0.f, 0.f, 0.f, 0.f};

  issue(0, 0);
  issue(1, 1);     // ns >= 2 always

  for (int t = 0; t < ns; ++t) {
    const int s = t & 1;
    const bool pf = (t + 2 < ns);

    // stage t complete: my 4 oldest loads done (4 newer stay in flight).
    if (t + 1 < ns) asm volatile("s_waitcnt vmcnt(4)" ::: "memory");
    else            asm volatile("s_waitcnt vmcnt(0)" ::: "memory");
    __builtin_amdgcn_s_barrier();
    __builtin_amdgcn_sched_barrier(0);

    // B fragments (4x): swizzled f32x4 pair, cvt_pk to bf16
    s16x8 bf[4];
#pragma unroll
    for (int nf = 0; nf < 4; ++nf) {
      int r = wn * 64 + nf * 16 + lr;
      int base = ((s * 2 + 1) * 256 + r) * BK;
      int x = ((r & 7) << 2);
      f32x4 lo = *(const f32x4*)&lds[base + ((lg * 8 + 0) ^ x)];
      f32x4 hi = *(const f32x4*)&lds[base + ((lg * 8 + 4) ^ x)];
      bf[nf] = cvt8(lo, hi);
    }

    // all waves done reading the B region -> B-loader waves refill it for
    // t+2 NOW (A region still being read below; LDS ranges are disjoint).
    asm volatile("s_waitcnt lgkmcnt(0)" ::: "memory");
    __builtin_amdgcn_s_barrier();
    __builtin_amdgcn_sched_barrier(0);
    if (mat == 1 && pf) issue(t + 2, s);

    // A fragments streamed; MFMA overlaps next frag's ds_read
#pragma unroll
    for (int mf = 0; mf < 4; ++mf) {
      int r = wm * 64 + mf * 16 + lr;
      int base = ((s * 2 + 0) * 256 + r) * BK;
      int x = ((r & 7) << 2);
      f32x4 lo = *(const f32x4*)&lds[base + ((lg * 8 + 0) ^ x)];
      f32x4 hi = *(const f32x4*)&lds[base + ((lg * 8 + 4) ^ x)];
      s16x8 af = cvt8(lo, hi);
#pragma unroll
      for (int nf = 0; nf < 4; ++nf)
        acc[mf][nf] = __builtin_amdgcn_mfma_f32_16x16x32_bf16(af, bf[nf], acc[mf][nf], 0, 0, 0);
    }

    // all waves done reading the A region -> A-loader waves refill it.
    asm volatile("s_waitcnt lgkmcnt(0)" ::: "memory");
    __builtin_amdgcn_s_barrier();
    __builtin_amdgcn_sched_barrier(0);
    if (mat == 0 && pf) issue(t + 2, s);
  }

  // C/D layout: col = lane&15, row = (lane>>4)*4 + reg. fp16 partials
  // (|partial| <~ 6*sqrt(1024) ~ 200 << 65504; zmean err ~1e-6 — R5-R13 proven).
  _Float16* Cp = ws + (size_t)blockIdx.x * (256 * 256);
#pragma unroll
  for (int mf = 0; mf < 4; ++mf) {
    int i0 = wm * 64 + mf * 16 + lg * 4;
#pragma unroll
    for (int nf = 0; nf < 4; ++nf) {
      int j = wn * 64 + nf * 16 + lr;
#pragma unroll
      for (int v = 0; v < 4; ++v)
        Cp[(size_t)(i0 + v) * 256 + j] = (_Float16)acc[mf][nf][v];
    }
  }
}

// Sum P fp16 partials, z = dot/D, BCE vs identity labels:
//   diag: softplus(z) - z ; off-diag: softplus(z)
// 8-way p-split x 128 threads handling j-pairs (uint loads).
__global__ void __launch_bounds__(1024)
loss_kernel(const _Float16* __restrict__ ws, float* __restrict__ out, int P, float invD) {
  const int i  = blockIdx.x;
  const int jh = threadIdx.x & 127;       // j-pair index (j = 2*jh, 2*jh+1)
  const int g8 = threadIdx.x >> 7;        // 0..7
  const int pc = P >> 3;                  // partials per group (P pow2 >= 8)

  const unsigned* base = (const unsigned*)(ws) + (size_t)(g8 * pc) * 32768
                         + i * 128 + jh;
  float s0 = 0.f, s1 = 0.f;
#pragma unroll 8
  for (int p = 0; p < pc; ++p) {
    unsigned u = base[(size_t)p * 32768];
    union { unsigned short h[2]; unsigned u; } cv; cv.u = u;
    s0 += (float)(*(const _Float16*)&cv.h[0]);
    s1 += (float)(*(const _Float16*)&cv.h[1]);
  }

  __shared__ float sred[8 * 256];
  sred[g8 * 256 + jh * 2 + 0] = s0;
  sred[g8 * 256 + jh * 2 + 1] = s1;
  __syncthreads();

  __shared__ float red[256];
  if (threadIdx.x < 256) {
    const int j = threadIdx.x;
    float z = 0.f;
#pragma unroll
    for (int g = 0; g < 8; ++g) z += sred[g * 256 + j];
    z *= invD;
    red[j] = log1pf(expf(z)) - (i == j ? z : 0.f);
  }
  __syncthreads();
  for (int st = 128; st > 0; st >>= 1) {
    if (threadIdx.x < st) red[threadIdx.x] += red[threadIdx.x + st];
    __syncthreads();
  }
  if (threadIdx.x == 0) atomicAdd(out, red[0] * (1.f / 65536.f));
}

extern "C" void kernel_launch(void* const* d_in, const int* in_sizes, int n_in,
                              void* d_out, int out_size, void* d_ws, size_t ws_size,
                              hipStream_t stream) {
  const float* V1 = (const float*)d_in[0];
  const float* V2 = (const float*)d_in[1];
  float* out = (float*)d_out;
  _Float16* ws = (_Float16*)d_ws;

  const int N = 256;
  const int D = in_sizes[0] / N;   // 262144

  int P = NCHUNK;                  // 256 fp16 partials = 32 MB
  while (P > 8 && (size_t)P * 65536 * sizeof(_Float16) > ws_size) P >>= 1;
  const int KC = D / P;            // 1024

  zero_kernel<<<1, 64, 0, stream>>>(out);
  gemm_kernel<<<P, THREADS, 0, stream>>>(V1, V2, ws, D, KC);
  loss_kernel<<<N, 1024, 0, stream>>>(ws, out, P, 1.0f / (float)D);
}